// Round 1
// 1384.770 us; speedup vs baseline: 1.0401x; 1.0401x over previous
//
#include <hip/hip_runtime.h>
#include <hip/hip_bf16.h>
#include <math.h>

#define FEAT_IN 500
#define HID 64
#define KPAD 512
#define NKC 16         // K chunks of 32 (512/32)
#define MT_PER_WAVE 2

typedef unsigned int uint;
typedef unsigned short ushort;
typedef __attribute__((ext_vector_type(8))) short bf16x8;
typedef __attribute__((ext_vector_type(4))) float f32x4;

__device__ inline ushort f2bf(float f) {
    uint u = __float_as_uint(f);
    uint r = (u + 0x7fff + ((u >> 16) & 1)) >> 16;
    return (ushort)r;
}

// pack two fp32 -> (bf16(a) | bf16(b)<<16), RNE
__device__ inline uint pk2(float a, float b) {
    uint ua = __float_as_uint(a), ub = __float_as_uint(b);
    ua = ua + 0x7fff + ((ua >> 16) & 1);
    ub = ub + 0x7fff + ((ub >> 16) & 1);
    return (ua >> 16) | (ub & 0xffff0000u);
}

__device__ inline void bf8_unpack(const uint4 v, float f[8]) {
    f[0] = __uint_as_float(v.x << 16);
    f[1] = __uint_as_float(v.x & 0xffff0000u);
    f[2] = __uint_as_float(v.y << 16);
    f[3] = __uint_as_float(v.y & 0xffff0000u);
    f[4] = __uint_as_float(v.z << 16);
    f[5] = __uint_as_float(v.z & 0xffff0000u);
    f[6] = __uint_as_float(v.w << 16);
    f[7] = __uint_as_float(v.w & 0xffff0000u);
}

// ---------------- degree count (over targets = col) ----------------
__global__ void deg_kernel(const int* __restrict__ col, int* __restrict__ deg, int E) {
    int e = blockIdx.x * blockDim.x + threadIdx.x;
    if (e < E) atomicAdd(&deg[col[e]], 1);
}

// ------------- parallel scan, 3 phases -------------
// phase 1: per-block (2048-elem chunk) sums
__global__ __launch_bounds__(256) void scan1_kernel(const int* __restrict__ deg,
                                                    int* __restrict__ bsum, int n) {
    __shared__ int red[4];
    int b = blockIdx.x, tid = threadIdx.x;
    int base = b * 2048;
    int s = 0;
#pragma unroll
    for (int k = 0; k < 8; k++) {
        int i = base + tid + k * 256;
        if (i < n) s += deg[i];
    }
#pragma unroll
    for (int d = 1; d < 64; d <<= 1) s += __shfl_xor(s, d);
    if ((tid & 63) == 0) red[tid >> 6] = s;
    __syncthreads();
    if (tid == 0) bsum[b] = red[0] + red[1] + red[2] + red[3];
}

// phase 2: single-wave exclusive scan of block sums (in place); also ptr[n]=E
__global__ void scan2_kernel(int* __restrict__ bsum, int* __restrict__ ptr,
                             int nb, int n, int E) {
    int lane = threadIdx.x;
    int run = 0;
    for (int base = 0; base < nb; base += 64) {
        int i = base + lane;
        int v = (i < nb) ? bsum[i] : 0;
        int sc = v;
#pragma unroll
        for (int d = 1; d < 64; d <<= 1) {
            int t = __shfl_up(sc, d);
            if (lane >= d) sc += t;
        }
        if (i < nb) bsum[i] = run + sc - v;
        run += __shfl(sc, 63);
    }
    if (lane == 0) ptr[n] = E;
}

// phase 3: per-block scan + apply block offset; emit ptr/cursor/dinv
__global__ __launch_bounds__(256) void scan3_kernel(const int* __restrict__ deg,
                                                    const int* __restrict__ bsum,
                                                    int* __restrict__ ptr,
                                                    int* __restrict__ cursor,
                                                    float* __restrict__ dinv, int n) {
    __shared__ int wsum[4];
    int b = blockIdx.x, tid = threadIdx.x;
    int lane = tid & 63, wv = tid >> 6;
    int base = b * 2048 + tid * 8;
    int v[8];
    int s = 0;
#pragma unroll
    for (int k = 0; k < 8; k++) {
        int i = base + k;
        v[k] = (i < n) ? deg[i] : 0;
        s += v[k];
    }
    int sc = s;
#pragma unroll
    for (int d = 1; d < 64; d <<= 1) {
        int t = __shfl_up(sc, d);
        if (lane >= d) sc += t;
    }
    if (lane == 63) wsum[wv] = sc;
    __syncthreads();
    int woff = 0;
    for (int w = 0; w < wv; w++) woff += wsum[w];
    int ex = bsum[b] + woff + sc - s;  // exclusive prefix of this thread's first elem
#pragma unroll
    for (int k = 0; k < 8; k++) {
        int i = base + k;
        if (i < n) {
            ptr[i] = ex;
            cursor[i] = ex;
            dinv[i] = rsqrtf((float)(v[k] + 1));  // +1 self loop
        }
        ex += v[k];
    }
}

// ---------------- scatter edges into CSR (sorted by target) ----------------
// weights are folded into the propagated state (s = dinv*u), so only src is stored.
__global__ void scatter_kernel(const int* __restrict__ row, const int* __restrict__ col,
                               int* __restrict__ cursor, int* __restrict__ csr_src, int E) {
    int e = blockIdx.x * blockDim.x + threadIdx.x;
    if (e < E) {
        int c = col[e];
        int p = atomicAdd(&cursor[c], 1);
        csr_src[p] = row[e];
    }
}

// -------- swizzle W1 (500x64, pad K->512) and W2 (64x64) into MFMA B-frag order --------
__global__ void swz_kernel(const float* __restrict__ W1, const float* __restrict__ W2,
                           ushort* __restrict__ w1s, ushort* __restrict__ w2s) {
    int idx = blockIdx.x * blockDim.x + threadIdx.x;  // [0, 36864)
    if (idx < 32768) {
        int j = idx & 7;
        int l = (idx >> 3) & 63;
        int t = (idx >> 9) & 3;
        int c = idx >> 11;
        int k = c * 32 + (l >> 4) * 8 + j;
        int nn = t * 16 + (l & 15);
        float v = (k < FEAT_IN) ? W1[(size_t)k * HID + nn] : 0.0f;
        w1s[idx] = f2bf(v);
    } else if (idx < 32768 + 4096) {
        int r = idx - 32768;
        int j = r & 7;
        int l = (r >> 3) & 63;
        int t = (r >> 9) & 3;
        int c = r >> 11;
        int k = c * 32 + (l >> 4) * 8 + j;
        int nn = t * 16 + (l & 15);
        w2s[r] = f2bf(W2[(size_t)k * HID + nn]);
    }
}

// ------------- MFMA MLP: h=relu(xW1+b1); h2=hW2+b2; A=bf16(dinv*h2); out=temp[0]*h2 -------------
__global__ __launch_bounds__(256) void mlp_kernel(const float* __restrict__ x,
                                                  const ushort* __restrict__ w1s,
                                                  const float* __restrict__ b1,
                                                  const ushort* __restrict__ w2s,
                                                  const float* __restrict__ b2,
                                                  const float* __restrict__ temp,
                                                  const float* __restrict__ dinv,
                                                  ushort* __restrict__ A,
                                                  float* __restrict__ out, int n) {
    __shared__ ushort hls[4][16 * 72];  // per-wave h1 tile, row stride 72 bf16
    const int lane = threadIdx.x & 63;
    const int wv = threadIdx.x >> 6;
    const int g = lane >> 4;
    const int c15 = lane & 15;
    const int nmt = (n + 15) / 16;
    int mt0 = (blockIdx.x * 4 + wv) * MT_PER_WAVE;
    if (mt0 >= nmt) return;

    float b1v[4], b2v[4];
#pragma unroll
    for (int t = 0; t < 4; t++) {
        b1v[t] = b1[t * 16 + c15];
        b2v[t] = b2[t * 16 + c15];
    }
    float t0 = temp[0];
    ushort* hl = hls[wv];

    for (int m = 0; m < MT_PER_WAVE; m++) {
        int mt = mt0 + m;
        if (mt >= nmt) break;
        int row = mt * 16 + c15;
        const float* xr = x + (size_t)row * FEAT_IN;
        bool rok = (row < n);

        f32x4 acc[4] = {{0.f, 0.f, 0.f, 0.f}, {0.f, 0.f, 0.f, 0.f},
                        {0.f, 0.f, 0.f, 0.f}, {0.f, 0.f, 0.f, 0.f}};

        // full K chunks 0..14 (k = 0..479)
        for (int c = 0; c < 15; c++) {
            int k = c * 32 + g * 8;
            float4 lo = {0.f, 0.f, 0.f, 0.f}, hi = {0.f, 0.f, 0.f, 0.f};
            if (rok) {
                lo = *(const float4*)(xr + k);
                hi = *(const float4*)(xr + k + 4);
            }
            uint4 au;
            au.x = pk2(lo.x, lo.y);
            au.y = pk2(lo.z, lo.w);
            au.z = pk2(hi.x, hi.y);
            au.w = pk2(hi.z, hi.w);
            bf16x8 a = *(bf16x8*)&au;
            const ushort* wp = w1s + ((size_t)c * 4) * 512 + lane * 8;
#pragma unroll
            for (int t = 0; t < 4; t++) {
                bf16x8 b = *(const bf16x8*)(wp + t * 512);
                acc[t] = __builtin_amdgcn_mfma_f32_16x16x32_bf16(a, b, acc[t], 0, 0, 0);
            }
        }
        // tail chunk c=15 (k = 480..511, valid < 500)
        {
            float v[8];
#pragma unroll
            for (int j = 0; j < 8; j++) {
                int k = 480 + g * 8 + j;
                v[j] = (rok && k < FEAT_IN) ? xr[k] : 0.0f;
            }
            uint4 au;
            au.x = pk2(v[0], v[1]);
            au.y = pk2(v[2], v[3]);
            au.z = pk2(v[4], v[5]);
            au.w = pk2(v[6], v[7]);
            bf16x8 a = *(bf16x8*)&au;
            const ushort* wp = w1s + (size_t)15 * 4 * 512 + lane * 8;
#pragma unroll
            for (int t = 0; t < 4; t++) {
                bf16x8 b = *(const bf16x8*)(wp + t * 512);
                acc[t] = __builtin_amdgcn_mfma_f32_16x16x32_bf16(a, b, acc[t], 0, 0, 0);
            }
        }

        // h1 = relu(acc + b1) -> LDS (bf16, row stride 72)
#pragma unroll
        for (int t = 0; t < 4; t++) {
#pragma unroll
            for (int r = 0; r < 4; r++) {
                float h = fmaxf(acc[t][r] + b1v[t], 0.0f);
                hl[(g * 4 + r) * 72 + t * 16 + c15] = f2bf(h);
            }
        }

        // GEMM2: h1(16x64) @ W2(64x64)
        f32x4 acc2[4] = {{0.f, 0.f, 0.f, 0.f}, {0.f, 0.f, 0.f, 0.f},
                         {0.f, 0.f, 0.f, 0.f}, {0.f, 0.f, 0.f, 0.f}};
#pragma unroll
        for (int c2 = 0; c2 < 2; c2++) {
            bf16x8 a2 = *(const bf16x8*)(hl + c15 * 72 + c2 * 32 + g * 8);
            const ushort* wp2 = w2s + ((size_t)c2 * 4) * 512 + lane * 8;
#pragma unroll
            for (int t = 0; t < 4; t++) {
                bf16x8 b = *(const bf16x8*)(wp2 + t * 512);
                acc2[t] = __builtin_amdgcn_mfma_f32_16x16x32_bf16(a2, b, acc2[t], 0, 0, 0);
            }
        }

        // epilogue: A = bf16(dinv*h2)  (scaled state s0); out = temp[0]*h2
        float dvr[4];
#pragma unroll
        for (int r = 0; r < 4; r++) {
            int orow = mt * 16 + g * 4 + r;
            dvr[r] = (orow < n) ? dinv[orow] : 0.0f;
        }
#pragma unroll
        for (int t = 0; t < 4; t++) {
#pragma unroll
            for (int r = 0; r < 4; r++) {
                int orow = mt * 16 + g * 4 + r;
                if (orow < n) {
                    float d = acc2[t][r] + b2v[t];
                    size_t o = (size_t)orow * HID + t * 16 + c15;
                    A[o] = f2bf(dvr[r] * d);
                    out[o] = t0 * d;
                }
            }
        }
    }
}

// ------------- one propagation hop on scaled state s = dinv*u -------------
// T_i = sum_{j in N(i)} s[j] + s[i];  out += temp*dinv[i]*T_i;  s_next[i] = dinv[i]^2*T_i
__global__ __launch_bounds__(256) void hop_kernel(const int* __restrict__ ptr,
                                                  const int* __restrict__ csr_src,
                                                  const float* __restrict__ dinv,
                                                  const ushort* __restrict__ cur,
                                                  ushort* __restrict__ nxt,
                                                  float* __restrict__ out,
                                                  const float* __restrict__ temp,
                                                  int tidx, int n) {
    int i = (blockIdx.x * blockDim.x + threadIdx.x) >> 6;
    int lane = threadIdx.x & 63;
    if (i >= n) return;
    const int g = lane >> 3;
    const int q = lane & 7;

    int s = ptr[i];
    int e = ptr[i + 1];
    const uint* curu = (const uint*)cur;

    float acc[8] = {0.f, 0.f, 0.f, 0.f, 0.f, 0.f, 0.f, 0.f};
    float accB[8] = {0.f, 0.f, 0.f, 0.f, 0.f, 0.f, 0.f, 0.f};

    int p = s;
    for (; p + 16 <= e; p += 16) {
        int j0 = csr_src[p + g];
        int j1 = csr_src[p + 8 + g];
        uint4 v0 = *(const uint4*)(curu + (size_t)j0 * 32 + q * 4);
        uint4 v1 = *(const uint4*)(curu + (size_t)j1 * 32 + q * 4);
        float f0[8], f1[8];
        bf8_unpack(v0, f0);
        bf8_unpack(v1, f1);
#pragma unroll
        for (int t = 0; t < 8; t++) acc[t] += f0[t];
#pragma unroll
        for (int t = 0; t < 8; t++) accB[t] += f1[t];
    }
    for (; p < e; p += 8) {
        int pe = p + g;
        bool ok = pe < e;
        int pc = ok ? pe : (e - 1);
        int j = csr_src[pc];
        float w = ok ? 1.0f : 0.0f;
        uint4 v = *(const uint4*)(curu + (size_t)j * 32 + q * 4);
        float f[8];
        bf8_unpack(v, f);
#pragma unroll
        for (int t = 0; t < 8; t++) acc[t] += w * f[t];
    }
#pragma unroll
    for (int t = 0; t < 8; t++) acc[t] += accB[t];

#pragma unroll
    for (int m = 8; m <= 32; m <<= 1) {
#pragma unroll
        for (int t = 0; t < 8; t++) acc[t] += __shfl_xor(acc[t], m);
    }

    // self term: + s[i]
    uint4 sv = *(const uint4*)(curu + (size_t)i * 32 + q * 4);
    float sf[8];
    bf8_unpack(sv, sf);
#pragma unroll
    for (int t = 0; t < 8; t++) acc[t] += sf[t];

    if (lane < 8) {
        float d = dinv[i];
        float dd = d * d;
        float tk = temp[tidx] * d;
        uint4 pk;
        pk.x = (uint)f2bf(dd * acc[0]) | ((uint)f2bf(dd * acc[1]) << 16);
        pk.y = (uint)f2bf(dd * acc[2]) | ((uint)f2bf(dd * acc[3]) << 16);
        pk.z = (uint)f2bf(dd * acc[4]) | ((uint)f2bf(dd * acc[5]) << 16);
        pk.w = (uint)f2bf(dd * acc[6]) | ((uint)f2bf(dd * acc[7]) << 16);
        *(uint4*)((uint*)nxt + (size_t)i * 32 + q * 4) = pk;

        float* op = out + (size_t)i * HID + q * 8;
        float4 o0 = *(const float4*)(op);
        float4 o1 = *(const float4*)(op + 4);
        o0.x += tk * acc[0]; o0.y += tk * acc[1]; o0.z += tk * acc[2]; o0.w += tk * acc[3];
        o1.x += tk * acc[4]; o1.y += tk * acc[5]; o1.z += tk * acc[6]; o1.w += tk * acc[7];
        *(float4*)(op) = o0;
        *(float4*)(op + 4) = o1;
    }
}

// ---------------- row log-softmax over 64 cols ----------------
__global__ __launch_bounds__(256) void lsm_kernel(float* __restrict__ out, int n) {
    int i = (blockIdx.x * blockDim.x + threadIdx.x) >> 6;
    int lane = threadIdx.x & 63;
    if (i >= n) return;
    size_t o = (size_t)i * HID + lane;
    float v = out[o];
    float m = v;
#pragma unroll
    for (int d = 32; d >= 1; d >>= 1) m = fmaxf(m, __shfl_xor(m, d));
    float ex = expf(v - m);
#pragma unroll
    for (int d = 32; d >= 1; d >>= 1) ex += __shfl_xor(ex, d);
    out[o] = v - m - logf(ex);
}

extern "C" void kernel_launch(void* const* d_in, const int* in_sizes, int n_in,
                              void* d_out, int out_size, void* d_ws, size_t ws_size,
                              hipStream_t stream) {
    const float* x    = (const float*)d_in[0];
    const int*   ei   = (const int*)d_in[1];
    const float* W1   = (const float*)d_in[2];
    const float* b1   = (const float*)d_in[3];
    const float* W2   = (const float*)d_in[4];
    const float* b2   = (const float*)d_in[5];
    const float* temp = (const float*)d_in[6];

    int n = in_sizes[0] / FEAT_IN;
    int E = in_sizes[1] / 2;
    int K = in_sizes[6] - 1;
    const int* row = ei;
    const int* col = ei + E;

    char* ws = (char*)d_ws;
    size_t off = 0;
    auto alloc = [&](size_t bytes) -> void* {
        void* p = (void*)(ws + off);
        off += (bytes + 255) & ~(size_t)255;
        return p;
    };
    size_t nf = (size_t)n * HID;
    int nb = (n + 2047) / 2048;
    ushort* A      = (ushort*)alloc(nf * sizeof(ushort));
    ushort* B      = (ushort*)alloc(nf * sizeof(ushort));
    float* dinv    = (float*)alloc((size_t)n * sizeof(float));
    int*   deg     = (int*)alloc((size_t)n * sizeof(int));
    int*   ptr     = (int*)alloc((size_t)(n + 1) * sizeof(int));
    int*   cursor  = (int*)alloc((size_t)n * sizeof(int));
    int*   bsum    = (int*)alloc((size_t)nb * sizeof(int));
    int*   csr_src = (int*)alloc((size_t)E * sizeof(int));
    ushort* w1s    = (ushort*)alloc(32768 * sizeof(ushort));
    ushort* w2s    = (ushort*)alloc(4096 * sizeof(ushort));
    (void)ws_size;

    float* out = (float*)d_out;

    hipMemsetAsync(deg, 0, (size_t)n * sizeof(int), stream);

    int eb = (E + 255) / 256;
    deg_kernel<<<eb, 256, 0, stream>>>(col, deg, E);
    scan1_kernel<<<nb, 256, 0, stream>>>(deg, bsum, n);
    scan2_kernel<<<1, 64, 0, stream>>>(bsum, ptr, nb, n, E);
    scan3_kernel<<<nb, 256, 0, stream>>>(deg, bsum, ptr, cursor, dinv, n);
    scatter_kernel<<<eb, 256, 0, stream>>>(row, col, cursor, csr_src, E);
    swz_kernel<<<(32768 + 4096 + 255) / 256, 256, 0, stream>>>(W1, W2, w1s, w2s);

    int nmt = (n + 15) / 16;
    int mlp_blocks = (nmt + 4 * MT_PER_WAVE - 1) / (4 * MT_PER_WAVE);
    mlp_kernel<<<mlp_blocks, 256, 0, stream>>>(x, w1s, b1, w2s, b2, temp, dinv, A, out, n);

    int hop_blocks = (n + 3) / 4;
    ushort* cur = A;
    ushort* nxt = B;
    for (int k = 0; k < K; k++) {
        hop_kernel<<<hop_blocks, 256, 0, stream>>>(ptr, csr_src, dinv, cur, nxt, out,
                                                   temp, k + 1, n);
        ushort* t = cur; cur = nxt; nxt = t;
    }

    lsm_kernel<<<hop_blocks, 256, 0, stream>>>(out, n);
}

// Round 2
// 1085.506 us; speedup vs baseline: 1.3269x; 1.2757x over previous
//
#include <hip/hip_runtime.h>
#include <hip/hip_bf16.h>
#include <math.h>

#define FEAT_IN 500
#define HID 64
#define MT_PER_WAVE 2
#define NPB 128        // nodes per bucket
#define MAXB 1024      // max buckets (supports n <= 131072)

typedef unsigned int uint;
typedef unsigned short ushort;
typedef __attribute__((ext_vector_type(8))) short bf16x8;
typedef __attribute__((ext_vector_type(4))) float f32x4;

__device__ inline ushort f2bf(float f) {
    uint u = __float_as_uint(f);
    uint r = (u + 0x7fff + ((u >> 16) & 1)) >> 16;
    return (ushort)r;
}

// pack two fp32 -> (bf16(a) | bf16(b)<<16), RNE
__device__ inline uint pk2(float a, float b) {
    uint ua = __float_as_uint(a), ub = __float_as_uint(b);
    ua = ua + 0x7fff + ((ua >> 16) & 1);
    ub = ub + 0x7fff + ((ub >> 16) & 1);
    return (ua >> 16) | (ub & 0xffff0000u);
}

__device__ inline void bf8_unpack(const uint4 v, float f[8]) {
    f[0] = __uint_as_float(v.x << 16);
    f[1] = __uint_as_float(v.x & 0xffff0000u);
    f[2] = __uint_as_float(v.y << 16);
    f[3] = __uint_as_float(v.y & 0xffff0000u);
    f[4] = __uint_as_float(v.z << 16);
    f[5] = __uint_as_float(v.z & 0xffff0000u);
    f[6] = __uint_as_float(v.w << 16);
    f[7] = __uint_as_float(v.w & 0xffff0000u);
}

// ---------------- phase A: per-bucket edge counts (LDS-aggregated) ----------------
__global__ __launch_bounds__(256) void bcnt_kernel(const int* __restrict__ col,
                                                   int* __restrict__ bcnt, int E, int nbkt) {
    __shared__ int cnt[MAXB];
    int tid = threadIdx.x;
    for (int j = tid; j < nbkt; j += 256) cnt[j] = 0;
    __syncthreads();
    int stride = gridDim.x * 256;
    for (int e = blockIdx.x * 256 + tid; e < E; e += stride) {
        atomicAdd(&cnt[col[e] >> 7], 1);
    }
    __syncthreads();
    for (int j = tid; j < nbkt; j += 256) {
        int v = cnt[j];
        if (v) atomicAdd(&bcnt[j], v);
    }
}

// ---------------- phase B: scan bucket counts -> boff, bcur; ptr[n]=E ----------------
__global__ void bscan_kernel(const int* __restrict__ bcnt, int* __restrict__ boff,
                             int* __restrict__ bcur, int* __restrict__ ptr,
                             int nbkt, int n, int E) {
    int lane = threadIdx.x;  // 64 threads
    int run = 0;
    for (int base = 0; base < nbkt; base += 64) {
        int i = base + lane;
        int v = (i < nbkt) ? bcnt[i] : 0;
        int sc = v;
#pragma unroll
        for (int d = 1; d < 64; d <<= 1) {
            int t = __shfl_up(sc, d);
            if (lane >= d) sc += t;
        }
        if (i < nbkt) {
            int ex = run + sc - v;
            boff[i] = ex;
            bcur[i] = ex;
        }
        run += __shfl(sc, 63);
    }
    if (lane == 0) {
        boff[nbkt] = E;
        ptr[n] = E;
    }
}

// ---------------- phase C: block-aggregated bucketed scatter ----------------
// each block: LDS histogram of its chunk, one atomic reservation per bucket,
// then contiguous runs of packed (src<<7 | col&127) into csr_tmp.
__global__ __launch_bounds__(1024) void bscat_kernel(const int* __restrict__ row,
                                                     const int* __restrict__ col,
                                                     int* __restrict__ bcur,
                                                     uint* __restrict__ csr_tmp,
                                                     int E, int nbkt) {
    __shared__ int cnt[MAXB];
    __shared__ int pos[MAXB];
    int tid = threadIdx.x;
    int chunk = (E + gridDim.x - 1) / gridDim.x;
    int c0 = blockIdx.x * chunk;
    int c1 = min(E, c0 + chunk);
    for (int j = tid; j < nbkt; j += 1024) cnt[j] = 0;
    __syncthreads();
    for (int e = c0 + tid; e < c1; e += 1024) atomicAdd(&cnt[col[e] >> 7], 1);
    __syncthreads();
    for (int j = tid; j < nbkt; j += 1024) {
        int v = cnt[j];
        pos[j] = v ? atomicAdd(&bcur[j], v) : 0;
    }
    __syncthreads();
    for (int e = c0 + tid; e < c1; e += 1024) {
        int c = col[e];
        int j = c >> 7;
        int r = atomicAdd(&pos[j], 1);
        csr_tmp[r] = ((uint)row[e] << 7) | (uint)(c & (NPB - 1));
    }
}

// ---------------- phase D: per-bucket node sort -> csr_src, ptr, dinv ----------------
__global__ __launch_bounds__(256) void bsort_kernel(const uint* __restrict__ csr_tmp,
                                                    const int* __restrict__ boff,
                                                    int* __restrict__ ptr,
                                                    float* __restrict__ dinv,
                                                    int* __restrict__ csr_src,
                                                    int n) {
    __shared__ int degl[NPB];
    __shared__ int offl[NPB];
    int b = blockIdx.x;
    int tid = threadIdx.x;
    int t0 = boff[b], t1 = boff[b + 1];
    if (tid < NPB) degl[tid] = 0;
    __syncthreads();
    for (int p = t0 + tid; p < t1; p += 256) {
        uint pk = csr_tmp[p];
        atomicAdd(&degl[pk & (NPB - 1)], 1);
    }
    __syncthreads();
    // exclusive scan of degl[0..127] into offl (wave 0)
    if (tid < 64) {
        int v0 = degl[tid];
        int s0 = v0;
#pragma unroll
        for (int d = 1; d < 64; d <<= 1) {
            int t = __shfl_up(s0, d);
            if (tid >= d) s0 += t;
        }
        int tot0 = __shfl(s0, 63);
        int v1 = degl[64 + tid];
        int s1 = v1;
#pragma unroll
        for (int d = 1; d < 64; d <<= 1) {
            int t = __shfl_up(s1, d);
            if (tid >= d) s1 += t;
        }
        offl[tid] = s0 - v0;
        offl[64 + tid] = tot0 + s1 - v1;
    }
    __syncthreads();
    // per-node outputs (CSR is bucket-major + node-sorted within bucket)
    if (tid < NPB) {
        int node = b * NPB + tid;
        if (node < n) {
            ptr[node] = t0 + offl[tid];
            dinv[node] = rsqrtf((float)(degl[tid] + 1));  // +1 self loop
        }
    }
    __syncthreads();
    // scatter srcs into node-sorted positions (offl doubles as cursor)
    for (int p = t0 + tid; p < t1; p += 256) {
        uint pk = csr_tmp[p];
        int l = pk & (NPB - 1);
        int r = t0 + atomicAdd(&offl[l], 1);
        csr_src[r] = (int)(pk >> 7);
    }
}

// -------- swizzle W1 (500x64, pad K->512) and W2 (64x64) into MFMA B-frag order --------
__global__ void swz_kernel(const float* __restrict__ W1, const float* __restrict__ W2,
                           ushort* __restrict__ w1s, ushort* __restrict__ w2s) {
    int idx = blockIdx.x * blockDim.x + threadIdx.x;  // [0, 36864)
    if (idx < 32768) {
        int j = idx & 7;
        int l = (idx >> 3) & 63;
        int t = (idx >> 9) & 3;
        int c = idx >> 11;
        int k = c * 32 + (l >> 4) * 8 + j;
        int nn = t * 16 + (l & 15);
        float v = (k < FEAT_IN) ? W1[(size_t)k * HID + nn] : 0.0f;
        w1s[idx] = f2bf(v);
    } else if (idx < 32768 + 4096) {
        int r = idx - 32768;
        int j = r & 7;
        int l = (r >> 3) & 63;
        int t = (r >> 9) & 3;
        int c = r >> 11;
        int k = c * 32 + (l >> 4) * 8 + j;
        int nn = t * 16 + (l & 15);
        w2s[r] = f2bf(W2[(size_t)k * HID + nn]);
    }
}

// ------------- MFMA MLP: h=relu(xW1+b1); h2=hW2+b2; A=bf16(dinv*h2); out=temp[0]*h2 -------------
__global__ __launch_bounds__(256) void mlp_kernel(const float* __restrict__ x,
                                                  const ushort* __restrict__ w1s,
                                                  const float* __restrict__ b1,
                                                  const ushort* __restrict__ w2s,
                                                  const float* __restrict__ b2,
                                                  const float* __restrict__ temp,
                                                  const float* __restrict__ dinv,
                                                  ushort* __restrict__ A,
                                                  float* __restrict__ out, int n) {
    __shared__ ushort hls[4][16 * 72];  // per-wave h1 tile, row stride 72 bf16
    const int lane = threadIdx.x & 63;
    const int wv = threadIdx.x >> 6;
    const int g = lane >> 4;
    const int c15 = lane & 15;
    const int nmt = (n + 15) / 16;
    int mt0 = (blockIdx.x * 4 + wv) * MT_PER_WAVE;
    if (mt0 >= nmt) return;

    float b1v[4], b2v[4];
#pragma unroll
    for (int t = 0; t < 4; t++) {
        b1v[t] = b1[t * 16 + c15];
        b2v[t] = b2[t * 16 + c15];
    }
    float t0 = temp[0];
    ushort* hl = hls[wv];

    for (int m = 0; m < MT_PER_WAVE; m++) {
        int mt = mt0 + m;
        if (mt >= nmt) break;
        int row = mt * 16 + c15;
        const float* xr = x + (size_t)row * FEAT_IN;
        bool rok = (row < n);

        f32x4 acc[4] = {{0.f, 0.f, 0.f, 0.f}, {0.f, 0.f, 0.f, 0.f},
                        {0.f, 0.f, 0.f, 0.f}, {0.f, 0.f, 0.f, 0.f}};

        // full K chunks 0..14 (k = 0..479)
        for (int c = 0; c < 15; c++) {
            int k = c * 32 + g * 8;
            float4 lo = {0.f, 0.f, 0.f, 0.f}, hi = {0.f, 0.f, 0.f, 0.f};
            if (rok) {
                lo = *(const float4*)(xr + k);
                hi = *(const float4*)(xr + k + 4);
            }
            uint4 au;
            au.x = pk2(lo.x, lo.y);
            au.y = pk2(lo.z, lo.w);
            au.z = pk2(hi.x, hi.y);
            au.w = pk2(hi.z, hi.w);
            bf16x8 a = *(bf16x8*)&au;
            const ushort* wp = w1s + ((size_t)c * 4) * 512 + lane * 8;
#pragma unroll
            for (int t = 0; t < 4; t++) {
                bf16x8 b = *(const bf16x8*)(wp + t * 512);
                acc[t] = __builtin_amdgcn_mfma_f32_16x16x32_bf16(a, b, acc[t], 0, 0, 0);
            }
        }
        // tail chunk c=15 (k = 480..511, valid < 500)
        {
            float v[8];
#pragma unroll
            for (int j = 0; j < 8; j++) {
                int k = 480 + g * 8 + j;
                v[j] = (rok && k < FEAT_IN) ? xr[k] : 0.0f;
            }
            uint4 au;
            au.x = pk2(v[0], v[1]);
            au.y = pk2(v[2], v[3]);
            au.z = pk2(v[4], v[5]);
            au.w = pk2(v[6], v[7]);
            bf16x8 a = *(bf16x8*)&au;
            const ushort* wp = w1s + (size_t)15 * 4 * 512 + lane * 8;
#pragma unroll
            for (int t = 0; t < 4; t++) {
                bf16x8 b = *(const bf16x8*)(wp + t * 512);
                acc[t] = __builtin_amdgcn_mfma_f32_16x16x32_bf16(a, b, acc[t], 0, 0, 0);
            }
        }

        // h1 = relu(acc + b1) -> LDS (bf16, row stride 72)
#pragma unroll
        for (int t = 0; t < 4; t++) {
#pragma unroll
            for (int r = 0; r < 4; r++) {
                float h = fmaxf(acc[t][r] + b1v[t], 0.0f);
                hl[(g * 4 + r) * 72 + t * 16 + c15] = f2bf(h);
            }
        }

        // GEMM2: h1(16x64) @ W2(64x64)
        f32x4 acc2[4] = {{0.f, 0.f, 0.f, 0.f}, {0.f, 0.f, 0.f, 0.f},
                         {0.f, 0.f, 0.f, 0.f}, {0.f, 0.f, 0.f, 0.f}};
#pragma unroll
        for (int c2 = 0; c2 < 2; c2++) {
            bf16x8 a2 = *(const bf16x8*)(hl + c15 * 72 + c2 * 32 + g * 8);
            const ushort* wp2 = w2s + ((size_t)c2 * 4) * 512 + lane * 8;
#pragma unroll
            for (int t = 0; t < 4; t++) {
                bf16x8 b = *(const bf16x8*)(wp2 + t * 512);
                acc2[t] = __builtin_amdgcn_mfma_f32_16x16x32_bf16(a2, b, acc2[t], 0, 0, 0);
            }
        }

        // epilogue: A = bf16(dinv*h2)  (scaled state s0); out = temp[0]*h2
        float dvr[4];
#pragma unroll
        for (int r = 0; r < 4; r++) {
            int orow = mt * 16 + g * 4 + r;
            dvr[r] = (orow < n) ? dinv[orow] : 0.0f;
        }
#pragma unroll
        for (int t = 0; t < 4; t++) {
#pragma unroll
            for (int r = 0; r < 4; r++) {
                int orow = mt * 16 + g * 4 + r;
                if (orow < n) {
                    float d = acc2[t][r] + b2v[t];
                    size_t o = (size_t)orow * HID + t * 16 + c15;
                    A[o] = f2bf(dvr[r] * d);
                    out[o] = t0 * d;
                }
            }
        }
    }
}

// ------------- one propagation hop on scaled state s = dinv*u -------------
// T_i = sum_{j in N(i)} s[j] + s[i];  out += temp*dinv[i]*T_i;  s_next[i] = dinv[i]^2*T_i
__global__ __launch_bounds__(256) void hop_kernel(const int* __restrict__ ptr,
                                                  const int* __restrict__ csr_src,
                                                  const float* __restrict__ dinv,
                                                  const ushort* __restrict__ cur,
                                                  ushort* __restrict__ nxt,
                                                  float* __restrict__ out,
                                                  const float* __restrict__ temp,
                                                  int tidx, int n) {
    int i = (blockIdx.x * blockDim.x + threadIdx.x) >> 6;
    int lane = threadIdx.x & 63;
    if (i >= n) return;
    const int g = lane >> 3;
    const int q = lane & 7;

    int s = ptr[i];
    int e = ptr[i + 1];
    const uint* curu = (const uint*)cur;

    float acc[8] = {0.f, 0.f, 0.f, 0.f, 0.f, 0.f, 0.f, 0.f};
    float accB[8] = {0.f, 0.f, 0.f, 0.f, 0.f, 0.f, 0.f, 0.f};

    int p = s;
    for (; p + 16 <= e; p += 16) {
        int j0 = csr_src[p + g];
        int j1 = csr_src[p + 8 + g];
        uint4 v0 = *(const uint4*)(curu + (size_t)j0 * 32 + q * 4);
        uint4 v1 = *(const uint4*)(curu + (size_t)j1 * 32 + q * 4);
        float f0[8], f1[8];
        bf8_unpack(v0, f0);
        bf8_unpack(v1, f1);
#pragma unroll
        for (int t = 0; t < 8; t++) acc[t] += f0[t];
#pragma unroll
        for (int t = 0; t < 8; t++) accB[t] += f1[t];
    }
    for (; p < e; p += 8) {
        int pe = p + g;
        bool ok = pe < e;
        int pc = ok ? pe : (e - 1);
        int j = csr_src[pc];
        float w = ok ? 1.0f : 0.0f;
        uint4 v = *(const uint4*)(curu + (size_t)j * 32 + q * 4);
        float f[8];
        bf8_unpack(v, f);
#pragma unroll
        for (int t = 0; t < 8; t++) acc[t] += w * f[t];
    }
#pragma unroll
    for (int t = 0; t < 8; t++) acc[t] += accB[t];

#pragma unroll
    for (int m = 8; m <= 32; m <<= 1) {
#pragma unroll
        for (int t = 0; t < 8; t++) acc[t] += __shfl_xor(acc[t], m);
    }

    // self term: + s[i]
    uint4 sv = *(const uint4*)(curu + (size_t)i * 32 + q * 4);
    float sf[8];
    bf8_unpack(sv, sf);
#pragma unroll
    for (int t = 0; t < 8; t++) acc[t] += sf[t];

    if (lane < 8) {
        float d = dinv[i];
        float dd = d * d;
        float tk = temp[tidx] * d;
        uint4 pk;
        pk.x = (uint)f2bf(dd * acc[0]) | ((uint)f2bf(dd * acc[1]) << 16);
        pk.y = (uint)f2bf(dd * acc[2]) | ((uint)f2bf(dd * acc[3]) << 16);
        pk.z = (uint)f2bf(dd * acc[4]) | ((uint)f2bf(dd * acc[5]) << 16);
        pk.w = (uint)f2bf(dd * acc[6]) | ((uint)f2bf(dd * acc[7]) << 16);
        *(uint4*)((uint*)nxt + (size_t)i * 32 + q * 4) = pk;

        float* op = out + (size_t)i * HID + q * 8;
        float4 o0 = *(const float4*)(op);
        float4 o1 = *(const float4*)(op + 4);
        o0.x += tk * acc[0]; o0.y += tk * acc[1]; o0.z += tk * acc[2]; o0.w += tk * acc[3];
        o1.x += tk * acc[4]; o1.y += tk * acc[5]; o1.z += tk * acc[6]; o1.w += tk * acc[7];
        *(float4*)(op) = o0;
        *(float4*)(op + 4) = o1;
    }
}

// ---------------- row log-softmax over 64 cols ----------------
__global__ __launch_bounds__(256) void lsm_kernel(float* __restrict__ out, int n) {
    int i = (blockIdx.x * blockDim.x + threadIdx.x) >> 6;
    int lane = threadIdx.x & 63;
    if (i >= n) return;
    size_t o = (size_t)i * HID + lane;
    float v = out[o];
    float m = v;
#pragma unroll
    for (int d = 32; d >= 1; d >>= 1) m = fmaxf(m, __shfl_xor(m, d));
    float ex = expf(v - m);
#pragma unroll
    for (int d = 32; d >= 1; d >>= 1) ex += __shfl_xor(ex, d);
    out[o] = v - m - logf(ex);
}

extern "C" void kernel_launch(void* const* d_in, const int* in_sizes, int n_in,
                              void* d_out, int out_size, void* d_ws, size_t ws_size,
                              hipStream_t stream) {
    const float* x    = (const float*)d_in[0];
    const int*   ei   = (const int*)d_in[1];
    const float* W1   = (const float*)d_in[2];
    const float* b1   = (const float*)d_in[3];
    const float* W2   = (const float*)d_in[4];
    const float* b2   = (const float*)d_in[5];
    const float* temp = (const float*)d_in[6];

    int n = in_sizes[0] / FEAT_IN;
    int E = in_sizes[1] / 2;
    int K = in_sizes[6] - 1;
    const int* row = ei;
    const int* col = ei + E;
    int nbkt = (n + NPB - 1) >> 7;

    char* ws = (char*)d_ws;
    size_t off = 0;
    auto alloc = [&](size_t bytes) -> void* {
        void* p = (void*)(ws + off);
        off += (bytes + 255) & ~(size_t)255;
        return p;
    };
    size_t nf = (size_t)n * HID;
    ushort* A      = (ushort*)alloc(nf * sizeof(ushort));
    ushort* B      = (ushort*)alloc(nf * sizeof(ushort));
    float* dinv    = (float*)alloc((size_t)n * sizeof(float));
    int*   ptr     = (int*)alloc((size_t)(n + 1) * sizeof(int));
    int*   bcnt    = (int*)alloc((size_t)MAXB * sizeof(int));
    int*   boff    = (int*)alloc((size_t)(MAXB + 1) * sizeof(int));
    int*   bcur    = (int*)alloc((size_t)MAXB * sizeof(int));
    uint*  csr_tmp = (uint*)alloc((size_t)E * sizeof(uint));
    int*   csr_src = (int*)alloc((size_t)E * sizeof(int));
    ushort* w1s    = (ushort*)alloc(32768 * sizeof(ushort));
    ushort* w2s    = (ushort*)alloc(4096 * sizeof(ushort));
    (void)ws_size;

    float* out = (float*)d_out;

    hipMemsetAsync(bcnt, 0, (size_t)nbkt * sizeof(int), stream);

    bcnt_kernel<<<256, 256, 0, stream>>>(col, bcnt, E, nbkt);
    bscan_kernel<<<1, 64, 0, stream>>>(bcnt, boff, bcur, ptr, nbkt, n, E);
    bscat_kernel<<<256, 1024, 0, stream>>>(row, col, bcur, csr_tmp, E, nbkt);
    bsort_kernel<<<nbkt, 256, 0, stream>>>(csr_tmp, boff, ptr, dinv, csr_src, n);
    swz_kernel<<<(32768 + 4096 + 255) / 256, 256, 0, stream>>>(W1, W2, w1s, w2s);

    int nmt = (n + 15) / 16;
    int mlp_blocks = (nmt + 4 * MT_PER_WAVE - 1) / (4 * MT_PER_WAVE);
    mlp_kernel<<<mlp_blocks, 256, 0, stream>>>(x, w1s, b1, w2s, b2, temp, dinv, A, out, n);

    int hop_blocks = (n + 3) / 4;
    ushort* cur = A;
    ushort* nxt = B;
    for (int k = 0; k < K; k++) {
        hop_kernel<<<hop_blocks, 256, 0, stream>>>(ptr, csr_src, dinv, cur, nxt, out,
                                                   temp, k + 1, n);
        ushort* t = cur; cur = nxt; nxt = t;
    }

    lsm_kernel<<<hop_blocks, 256, 0, stream>>>(out, n);
}